// Round 12
// baseline (53.170 us; speedup 1.0000x reference)
//
#include <hip/hip_runtime.h>
#include <math.h>

#define H       2048
#define E       64
#define TOKENS  16384
#define BATCH   4
#define NBLK    256

typedef _Float16 f16x8  __attribute__((ext_vector_type(8)));
typedef float    f32x16 __attribute__((ext_vector_type(16)));

// ws float offsets
#define PART_OFF 0          // NBLK * 128 floats (psum[64] | cnt[64])

// LDS float offsets (64 KB arena; partials region reused after reduce)
#define SC_OFF   4224
#define HIST_OFF 8320

// ---- main: 256 blocks x 512 thr (1 block/CU); wave = ks 0..7 (K=256) ----
// Each wave: 64 tokens (2 A-tiles) x 64 experts; B read as fp32 W directly,
// hi/lo f16 split done in registers (same bytes as f16 hi+lo, no wconv pass).
// Fragment mapping (proven r5/r11): A row=la, k=kk*16+hi5*8+j;
// B e=et*32+la, k=kk*16+hi5*8+j; C/D row=(r&3)+8*(r>>2)+4*hi5, col=et*32+la.
__global__ __launch_bounds__(512, 2)
void router_main(const float* __restrict__ x,
                 const float* __restrict__ W,
                 float* __restrict__ out,
                 float* __restrict__ part)
{
    __shared__ float lds[16384];   // 64 KB

    const int tid = threadIdx.x;
    const int l   = tid & 63;
    const int ks  = tid >> 6;      // 0..7
    const int t0  = blockIdx.x * 64;

    const int la  = l & 31;
    const int hi5 = l >> 5;

    const float* xb0 = x + (size_t)(t0 + la) * H + ks * 256 + (hi5 << 3);
    const float* xb1 = xb0 + (size_t)32 * H;
    const float* wb  = W + (size_t)la * H + ks * 256 + (hi5 << 3);   // et stride 32*H

    f32x16 acc00, acc01, acc10, acc11;   // [tile][et]
    #pragma unroll
    for (int i = 0; i < 16; ++i) { acc00[i] = 0.f; acc01[i] = 0.f; acc10[i] = 0.f; acc11[i] = 0.f; }

    // A: 3-gen rotation (2-deep prefetch); B: 2-gen fp32 (1-deep)
    float4 Ar[3][4];     // [gen][tile0-lo, tile0-hi, tile1-lo, tile1-hi]
    float4 Bf[2][2][2];  // [gen][et][half]

    #pragma unroll
    for (int g = 0; g < 2; ++g) {
        Ar[g][0] = *(const float4*)(xb0 + g * 16);
        Ar[g][1] = *(const float4*)(xb0 + g * 16 + 4);
        Ar[g][2] = *(const float4*)(xb1 + g * 16);
        Ar[g][3] = *(const float4*)(xb1 + g * 16 + 4);
    }
    Bf[0][0][0] = *(const float4*)(wb);
    Bf[0][0][1] = *(const float4*)(wb + 4);
    Bf[0][1][0] = *(const float4*)(wb + (size_t)32 * H);
    Bf[0][1][1] = *(const float4*)(wb + (size_t)32 * H + 4);

    #pragma unroll
    for (int kk = 0; kk < 16; ++kk) {
        const int cg = kk % 3, ng = (kk + 2) % 3;
        const int cb = kk & 1, nb = (kk + 1) & 1;
        if (kk < 14) {
            Ar[ng][0] = *(const float4*)(xb0 + (kk + 2) * 16);
            Ar[ng][1] = *(const float4*)(xb0 + (kk + 2) * 16 + 4);
            Ar[ng][2] = *(const float4*)(xb1 + (kk + 2) * 16);
            Ar[ng][3] = *(const float4*)(xb1 + (kk + 2) * 16 + 4);
        }
        if (kk < 15) {
            Bf[nb][0][0] = *(const float4*)(wb + (kk + 1) * 16);
            Bf[nb][0][1] = *(const float4*)(wb + (kk + 1) * 16 + 4);
            Bf[nb][1][0] = *(const float4*)(wb + (size_t)32 * H + (kk + 1) * 16);
            Bf[nb][1][1] = *(const float4*)(wb + (size_t)32 * H + (kk + 1) * 16 + 4);
        }
        // A split
        const float xv0[8] = {Ar[cg][0].x, Ar[cg][0].y, Ar[cg][0].z, Ar[cg][0].w,
                              Ar[cg][1].x, Ar[cg][1].y, Ar[cg][1].z, Ar[cg][1].w};
        const float xv1[8] = {Ar[cg][2].x, Ar[cg][2].y, Ar[cg][2].z, Ar[cg][2].w,
                              Ar[cg][3].x, Ar[cg][3].y, Ar[cg][3].z, Ar[cg][3].w};
        f16x8 ah0, al0, ah1, al1;
        #pragma unroll
        for (int j = 0; j < 8; ++j) {
            const _Float16 h0 = (_Float16)xv0[j];
            ah0[j] = h0; al0[j] = (_Float16)(xv0[j] - (float)h0);
            const _Float16 h1 = (_Float16)xv1[j];
            ah1[j] = h1; al1[j] = (_Float16)(xv1[j] - (float)h1);
        }
        // B split (identical arithmetic to the old wconv pass)
        const float bv0[8] = {Bf[cb][0][0].x, Bf[cb][0][0].y, Bf[cb][0][0].z, Bf[cb][0][0].w,
                              Bf[cb][0][1].x, Bf[cb][0][1].y, Bf[cb][0][1].z, Bf[cb][0][1].w};
        const float bv1[8] = {Bf[cb][1][0].x, Bf[cb][1][0].y, Bf[cb][1][0].z, Bf[cb][1][0].w,
                              Bf[cb][1][1].x, Bf[cb][1][1].y, Bf[cb][1][1].z, Bf[cb][1][1].w};
        f16x8 bh0, bl0, bh1, bl1;
        #pragma unroll
        for (int j = 0; j < 8; ++j) {
            const _Float16 h0 = (_Float16)bv0[j];
            bh0[j] = h0; bl0[j] = (_Float16)(bv0[j] - (float)h0);
            const _Float16 h1 = (_Float16)bv1[j];
            bh1[j] = h1; bl1[j] = (_Float16)(bv1[j] - (float)h1);
        }
        acc00 = __builtin_amdgcn_mfma_f32_32x32x16_f16(ah0, bh0, acc00, 0, 0, 0);
        acc00 = __builtin_amdgcn_mfma_f32_32x32x16_f16(ah0, bl0, acc00, 0, 0, 0);
        acc00 = __builtin_amdgcn_mfma_f32_32x32x16_f16(al0, bh0, acc00, 0, 0, 0);
        acc01 = __builtin_amdgcn_mfma_f32_32x32x16_f16(ah0, bh1, acc01, 0, 0, 0);
        acc01 = __builtin_amdgcn_mfma_f32_32x32x16_f16(ah0, bl1, acc01, 0, 0, 0);
        acc01 = __builtin_amdgcn_mfma_f32_32x32x16_f16(al0, bh1, acc01, 0, 0, 0);
        acc10 = __builtin_amdgcn_mfma_f32_32x32x16_f16(ah1, bh0, acc10, 0, 0, 0);
        acc10 = __builtin_amdgcn_mfma_f32_32x32x16_f16(ah1, bl0, acc10, 0, 0, 0);
        acc10 = __builtin_amdgcn_mfma_f32_32x32x16_f16(al1, bh0, acc10, 0, 0, 0);
        acc11 = __builtin_amdgcn_mfma_f32_32x32x16_f16(ah1, bh1, acc11, 0, 0, 0);
        acc11 = __builtin_amdgcn_mfma_f32_32x32x16_f16(ah1, bl1, acc11, 0, 0, 0);
        acc11 = __builtin_amdgcn_mfma_f32_32x32x16_f16(al1, bh1, acc11, 0, 0, 0);
    }

    // ---- partials [4][64 t][64 e]: ks<4 store, then ks>=4 += (exact 2-addend sums)
    const int ksl = ks & 3;
    if (ks < 4) {
        #pragma unroll
        for (int r = 0; r < 16; ++r) {
            const int row = (r & 3) + 8 * (r >> 2) + 4 * hi5;
            lds[ksl * 4096 + row * 64 + la]             = acc00[r];
            lds[ksl * 4096 + row * 64 + 32 + la]        = acc01[r];
            lds[ksl * 4096 + (32 + row) * 64 + la]      = acc10[r];
            lds[ksl * 4096 + (32 + row) * 64 + 32 + la] = acc11[r];
        }
    }
    __syncthreads();
    if (ks >= 4) {
        #pragma unroll
        for (int r = 0; r < 16; ++r) {
            const int row = (r & 3) + 8 * (r >> 2) + 4 * hi5;
            lds[ksl * 4096 + row * 64 + la]             += acc00[r];
            lds[ksl * 4096 + row * 64 + 32 + la]        += acc01[r];
            lds[ksl * 4096 + (32 + row) * 64 + la]      += acc10[r];
            lds[ksl * 4096 + (32 + row) * 64 + 32 + la] += acc11[r];
        }
    }
    __syncthreads();

    // ---- reduce over 4 slots -> fin [64][65]
    {
        float4 s[2];
        #pragma unroll
        for (int rep = 0; rep < 2; ++rep) {
            const int t  = rep * 32 + (tid >> 4);
            const int c4 = (tid & 15) * 4;
            float4 a4 = make_float4(0.f, 0.f, 0.f, 0.f);
            #pragma unroll
            for (int k4 = 0; k4 < 4; ++k4) {
                const float4 v = *(const float4*)&lds[k4 * 4096 + t * 64 + c4];
                a4.x += v.x; a4.y += v.y; a4.z += v.z; a4.w += v.w;
            }
            s[rep] = a4;
        }
        __syncthreads();    // all partial reads done before overwrite
        #pragma unroll
        for (int rep = 0; rep < 2; ++rep) {
            const int t  = rep * 32 + (tid >> 4);
            const int c4 = (tid & 15) * 4;
            lds[t * 65 + c4 + 0] = s[rep].x;
            lds[t * 65 + c4 + 1] = s[rep].y;
            lds[t * 65 + c4 + 2] = s[rep].z;
            lds[t * 65 + c4 + 3] = s[rep].w;
        }
    }
    __syncthreads();

    // ---- wave-0 epilogue: 64 lanes = 64 tokens (proven serial structure)
    const int w = tid >> 6;
    int i1 = 0, i2 = 0;
    if (w == 0) {
        float lg[64];
        #pragma unroll
        for (int e = 0; e < 64; ++e) lg[e] = lds[l * 65 + e];
        float v1 = lg[0];
        #pragma unroll
        for (int e = 1; e < 64; ++e) { if (lg[e] > v1) { v1 = lg[e]; i1 = e; } }
        float v2 = -INFINITY;
        #pragma unroll
        for (int e = 0; e < 64; ++e) { if (e != i1 && lg[e] > v2) { v2 = lg[e]; i2 = e; } }
        float den = 0.f;
        #pragma unroll
        for (int e = 0; e < 64; ++e) den += __expf(lg[e] - v1);
        const float inv_den = 1.f / den;
        const float s1 = inv_den;                    // exp(v1-v1)/den
        const float s2 = __expf(v2 - v1) * inv_den;
        const float rs = 1.f / (s1 + s2 + 1e-20f);
        const int gt = t0 + l;
        *(float2*)&out[2 * gt]              = make_float2((float)i1, (float)i2);
        *(float2*)&out[2 * TOKENS + 2 * gt] = make_float2(s1 * rs, s2 * rs);
        // scores, rotated columns for conflict-free column sums
        #pragma unroll
        for (int e = 0; e < 64; ++e)
            lds[SC_OFF + l * 64 + ((e + l) & 63)] = __expf(lg[e] - v1) * inv_den;
        lds[HIST_OFF + l] = 0.f;
    }
    __syncthreads();
    if (w == 0) {
        atomicAdd(&lds[HIST_OFF + i1], 1.f);
        atomicAdd(&lds[HIST_OFF + i2], 1.f);
    }
    __syncthreads();
    if (w == 0) {
        float cs = 0.f;                  // expert l's score sum over 64 tokens
        #pragma unroll
        for (int r = 0; r < 64; ++r) cs += lds[SC_OFF + r * 64 + ((l + r) & 63)];
        part[blockIdx.x * 128 + l]      = cs;
        part[blockIdx.x * 128 + 64 + l] = lds[HIST_OFF + l];
    }
}

// ---- aux loss finalize: 1024 threads, 4-way split of the j loop (fixed order) ----
__global__ __launch_bounds__(1024)
void router_aux(const float* __restrict__ part, float* __restrict__ out)
{
    __shared__ float lps[1024], lct[1024], red[4];
    const int tid = threadIdx.x;
    const int q  = tid >> 8;        // 0..3
    const int be = tid & 255;       // b*64 + e
    const int b = be >> 6, e = be & 63;
    float ps = 0.f, ct = 0.f;
    #pragma unroll 4
    for (int j = q * 16; j < q * 16 + 16; ++j) {   // 64 blocks per batch
        const int base = (b * 64 + j) * 128;
        ps += part[base + e];                      // coalesced across e
        ct += part[base + 64 + e];
    }
    lps[tid] = ps; lct[tid] = ct;
    __syncthreads();
    if (tid < 256) {
        const float psf = lps[tid] + lps[tid + 256] + lps[tid + 512] + lps[tid + 768];
        const float ctf = lct[tid] + lct[tid + 256] + lct[tid + 512] + lct[tid + 768];
        // ce = ctf * E/(S*k); meanprob = psf/S
        float val = ctf * (64.0f / (4096.0f * 2.0f)) * (psf / 4096.0f);
        #pragma unroll
        for (int off = 32; off > 0; off >>= 1) val += __shfl_xor(val, off, 64);
        if ((tid & 63) == 0) red[tid >> 6] = val;
    }
    __syncthreads();
    if (tid == 0)
        out[4 * TOKENS] = (red[0] + red[1] + red[2] + red[3]) * (0.001f / 4.0f);
}

extern "C" void kernel_launch(void* const* d_in, const int* in_sizes, int n_in,
                              void* d_out, int out_size, void* d_ws, size_t ws_size,
                              hipStream_t stream)
{
    (void)in_sizes; (void)n_in; (void)out_size; (void)ws_size;
    const float* x = (const float*)d_in[0];
    const float* W = (const float*)d_in[1];
    float* out = (float*)d_out;
    float* ws  = (float*)d_ws;

    float* part = ws + PART_OFF;

    hipLaunchKernelGGL(router_main, dim3(NBLK), dim3(512), 0, stream,
                       x, W, out, part);
    hipLaunchKernelGGL(router_aux, dim3(1), dim3(1024), 0, stream, part, out);
}